// Round 12
// baseline (84.893 us; speedup 1.0000x reference)
//
#include <hip/hip_runtime.h>

typedef __attribute__((ext_vector_type(8))) short bf16x8;
typedef __attribute__((ext_vector_type(4))) float f32x4;
typedef __attribute__((ext_vector_type(8))) unsigned short u16x8;
typedef __attribute__((ext_vector_type(2))) unsigned u32x2;
typedef __attribute__((ext_vector_type(4))) unsigned u32x4u;

#define DM 2048
#define DI 4096
#define BATCH 128

__device__ __forceinline__ unsigned short f2bf(float f) {
  union { float f; unsigned u; } v; v.f = f;
  unsigned r = v.u + 0x7FFFu + ((v.u >> 16) & 1u);
  return (unsigned short)(r >> 16);
}
__device__ __forceinline__ float bf2f(unsigned short u) {
  union { unsigned u; float f; } v; v.u = (unsigned)u << 16; return v.f;
}
__device__ __forceinline__ unsigned pk2bf(float lo, float hi) {
  unsigned r;
  asm("v_cvt_pk_bf16_f32 %0, %1, %2" : "=v"(r) : "v"(lo), "v"(hi));
  return r;
}
__device__ __forceinline__ float sigm(float x) { return 1.f / (1.f + __expf(-x)); }

constexpr int BK = 64;
constexpr int LDT = BK + 8;

// ============================================================================
// gemmS: BM=128, BN=32, BK=64. A (bf16) LDS-staged double-buffered (36.9 KB ->
// 4 blocks/CU); B (f32 weights) STREAMED global->regs->cvt->MFMA, depth-1
// named-reg prefetch (loads for step t+1 issued before compute(t) -> counted
// vmcnt, ~32KB/block in flight). 4 waves 2Mx2N; wave tile 64x16.
// B fragment loads are full-line coalesced: 16 rows x 128B per wave per step.
// ============================================================================
#define LDA_S(AR, kb_) do { int kb = (kb_);                                   \
    _Pragma("unroll") for (int i = 0; i < 4; ++i) {                           \
      int idx = tid + i * 256, r = idx >> 3, c = (idx & 7) * 8;               \
      AR[i] = *(const u16x8*)&Ab[(long)r * lda + kb + c];                     \
    } } while (0)

#define STA_S(AR, buf_) do {                                                  \
    unsigned short* As_ = lds + (buf_) * (128 * LDT);                         \
    _Pragma("unroll") for (int i = 0; i < 4; ++i) {                           \
      int idx = tid + i * 256, r = idx >> 3, c = (idx & 7) * 8;               \
      *(u16x8*)&As_[r * LDT + c] = AR[i];                                     \
    } } while (0)

#define LDB_S(BB, kb_) do { int kb = (kb_);                                   \
    const float* bp = &Bg[(long)nrow * ldb + kb + lhi * 8];                   \
    BB[0] = *(const f32x4*)bp;       BB[1] = *(const f32x4*)(bp + 4);         \
    BB[2] = *(const f32x4*)(bp + 32); BB[3] = *(const f32x4*)(bp + 36);       \
  } while (0)

#define CMP_S(buf_, BB) do {                                                  \
    const unsigned short* As_ = lds + (buf_) * (128 * LDT);                   \
    _Pragma("unroll") for (int q = 0; q < 2; ++q) {                           \
      int kr = q * 32 + lhi * 8;                                              \
      bf16x8 af[4];                                                           \
      _Pragma("unroll") for (int mi = 0; mi < 4; ++mi)                        \
        af[mi] = *(const bf16x8*)&As_[(wm * 64 + mi * 16 + llo) * LDT + kr];  \
      union { u32x4u u; bf16x8 h; } cv;                                       \
      cv.u[0] = pk2bf(BB[2 * q][0], BB[2 * q][1]);                            \
      cv.u[1] = pk2bf(BB[2 * q][2], BB[2 * q][3]);                            \
      cv.u[2] = pk2bf(BB[2 * q + 1][0], BB[2 * q + 1][1]);                    \
      cv.u[3] = pk2bf(BB[2 * q + 1][2], BB[2 * q + 1][3]);                    \
      _Pragma("unroll") for (int mi = 0; mi < 4; ++mi)                        \
        acc[mi] = __builtin_amdgcn_mfma_f32_16x16x32_bf16(af[mi], cv.h, acc[mi], 0, 0, 0); \
    } } while (0)

// requires nt = (k1-k0)/BK >= 2
__device__ __forceinline__ void gemmS(const unsigned short* __restrict__ Ab, int lda,
                                      const float* __restrict__ Bg, int ldb,
                                      int n0, int k0, int k1, unsigned short* lds,
                                      f32x4* acc) {
  const int tid = threadIdx.x, lane = tid & 63, wave = tid >> 6;
  const int wm = wave >> 1, wn = wave & 1, llo = lane & 15, lhi = lane >> 4;
  const int nrow = n0 + wn * 16 + llo;  // this lane's B row (output column)

  u16x8 ar0[4], ar1[4];
  f32x4 bB0[4], bB1[4];

  const int nt = (k1 - k0) / BK;
  LDA_S(ar0, k0);
  LDA_S(ar1, k0 + BK);
  LDB_S(bB0, k0);
  STA_S(ar0, 0);
  __syncthreads();
  int t = 0;
  while (true) {
    // even: compute buf0 with bB0
    if (t + 1 < nt) LDB_S(bB1, k0 + (t + 1) * BK);
    if (t + 2 < nt) LDA_S(ar0, k0 + (t + 2) * BK);
    CMP_S(0, bB0);
    if (t + 1 < nt) STA_S(ar1, 1);
    __syncthreads();
    if (++t == nt) break;
    // odd: compute buf1 with bB1
    if (t + 1 < nt) LDB_S(bB0, k0 + (t + 1) * BK);
    if (t + 2 < nt) LDA_S(ar1, k0 + (t + 2) * BK);
    CMP_S(1, bB1);
    if (t + 1 < nt) STA_S(ar0, 0);
    __syncthreads();
    if (++t == nt) break;
  }
}

// ---- gemmMN (R10) kept for k45 (f32 A, 32x32 tile) ----
#define LDREGS(ARF, BR, kb_) do { int kb = (kb_);                                         \
    _Pragma("unroll") for (int i = 0; i < 2; ++i) {                                       \
      int idx = tid + i * 256, r = idx >> 4, c = (idx & 15) * 4;                          \
      ARF[i] = *(const f32x4*)&((const float*)Ag)[(long)(m0 + r) * lda + kb + c];         \
    }                                                                                     \
    _Pragma("unroll") for (int i = 0; i < 2; ++i) {                                       \
      int idx = tid + i * 256, r = idx >> 4, c = (idx & 15) * 4;                          \
      BR[i] = *(const f32x4*)&Bg[(long)(n0 + r) * ldb + kb + c];                          \
    } } while (0)

#define STLDS(ARF, BR, buf_) do {                                                         \
    unsigned short* As_ = lds + (buf_) * BUF;                                             \
    unsigned short* Bs_ = As_ + 32 * LDT;                                                 \
    _Pragma("unroll") for (int i = 0; i < 2; ++i) {                                       \
      int idx = tid + i * 256, r = idx >> 4, c = (idx & 15) * 4;                          \
      u32x2 o; o[0] = pk2bf(ARF[i][0], ARF[i][1]); o[1] = pk2bf(ARF[i][2], ARF[i][3]);   \
      *(u32x2*)&As_[r * LDT + c] = o;                                                     \
    }                                                                                     \
    _Pragma("unroll") for (int i = 0; i < 2; ++i) {                                       \
      int idx = tid + i * 256, r = idx >> 4, c = (idx & 15) * 4;                          \
      u32x2 o; o[0] = pk2bf(BR[i][0], BR[i][1]); o[1] = pk2bf(BR[i][2], BR[i][3]);       \
      *(u32x2*)&Bs_[r * LDT + c] = o;                                                     \
    } } while (0)

#define COMPUTE(buf_) do {                                                                \
    const unsigned short* As_ = lds + (buf_) * BUF;                                       \
    const unsigned short* Bs_ = As_ + 32 * LDT;                                           \
    _Pragma("unroll") for (int kk = 0; kk < BK; kk += 32) {                               \
      int kr = kk + lhi * 8;                                                              \
      bf16x8 af = *(const bf16x8*)&As_[(wm * 16 + llo) * LDT + kr];                       \
      bf16x8 bfr = *(const bf16x8*)&Bs_[(wn * 16 + llo) * LDT + kr];                      \
      acc[0] = __builtin_amdgcn_mfma_f32_16x16x32_bf16(af, bfr, acc[0], 0, 0, 0);         \
    } } while (0)

// 32x32 tile, f32 A; requires nt >= 2
__device__ __forceinline__ void gemm32(const void* Ag, int lda, const float* Bg, int ldb,
                                       int m0, int n0, int k0, int k1, unsigned short* lds,
                                       f32x4* acc) {
  constexpr int BUF = 64 * LDT;
  const int tid = threadIdx.x, lane = tid & 63, wave = tid >> 6;
  const int wm = wave >> 1, wn = wave & 1, llo = lane & 15, lhi = lane >> 4;
  f32x4 arf0[2], arf1[2], br0[2], br1[2];
  const int nt = (k1 - k0) / BK;
  LDREGS(arf0, br0, k0);
  LDREGS(arf1, br1, k0 + BK);
  STLDS(arf0, br0, 0);
  __syncthreads();
  int t = 0;
  while (true) {
    if (t + 2 < nt) LDREGS(arf0, br0, k0 + (t + 2) * BK);
    COMPUTE(0);
    if (t + 1 < nt) STLDS(arf1, br1, 1);
    __syncthreads();
    if (++t == nt) break;
    if (t + 2 < nt) LDREGS(arf1, br1, k0 + (t + 2) * BK);
    COMPUTE(1);
    if (t + 1 < nt) STLDS(arf0, br0, 0);
    __syncthreads();
    if (++t == nt) break;
  }
}

// ---------------- K1: RMSNorm -> normed (bf16) ----------------
__global__ __launch_bounds__(256) void k1_rmsnorm(const float* __restrict__ hs,
                                                  const float* __restrict__ nw,
                                                  unsigned short* __restrict__ normed) {
  int b = blockIdx.x, tid = threadIdx.x;
  const float* xr = hs + (long)b * DM;
  f32x4 v0 = *(const f32x4*)&xr[tid * 4];
  f32x4 v1 = *(const f32x4*)&xr[(tid + 256) * 4];
  float ss = v0[0]*v0[0] + v0[1]*v0[1] + v0[2]*v0[2] + v0[3]*v0[3]
           + v1[0]*v1[0] + v1[1]*v1[1] + v1[2]*v1[2] + v1[3]*v1[3];
  for (int off = 32; off; off >>= 1) ss += __shfl_xor(ss, off);
  __shared__ float red[4];
  if ((tid & 63) == 0) red[tid >> 6] = ss;
  __syncthreads();
  ss = red[0] + red[1] + red[2] + red[3];
  float rstd = rsqrtf(ss * (1.f / DM) + 1e-5f);
  f32x4 w0 = *(const f32x4*)&nw[tid * 4];
  f32x4 w1 = *(const f32x4*)&nw[(tid + 256) * 4];
  u32x2 o0, o1;
  o0[0] = pk2bf(v0[0] * rstd * w0[0], v0[1] * rstd * w0[1]);
  o0[1] = pk2bf(v0[2] * rstd * w0[2], v0[3] * rstd * w0[3]);
  o1[0] = pk2bf(v1[0] * rstd * w1[0], v1[1] * rstd * w1[1]);
  o1[1] = pk2bf(v1[2] * rstd * w1[2], v1[3] * rstd * w1[3]);
  *(u32x2*)&normed[(long)b * DM + tid * 4] = o0;
  *(u32x2*)&normed[(long)b * DM + (tid + 256) * 4] = o1;
}

// ---------------- K2: in_proj GEMM (128x8192x2048), gemmS, SK=4, bf16 partials ----------------
__global__ __launch_bounds__(256, 4) void k2_inproj(const unsigned short* __restrict__ normed,
                                                    const float* __restrict__ W,
                                                    unsigned short* __restrict__ xzp) {
  __shared__ unsigned short lds[2 * 128 * LDT];  // 36.9 KB
  f32x4 acc[4] = {};
  int bn = blockIdx.x, sk = blockIdx.y;
  gemmS(normed, DM, W, DM, bn * 32, sk * 512, sk * 512 + 512, lds, acc);
  int tid = threadIdx.x, lane = tid & 63, wave = tid >> 6, wm = wave >> 1, wn = wave & 1;
  int llo = lane & 15, lhi = lane >> 4;
  int n = bn * 32 + wn * 16 + llo;
  unsigned short* dst = xzp + (long)sk * (BATCH * 8192);
#pragma unroll
  for (int mi = 0; mi < 4; ++mi)
#pragma unroll
    for (int r = 0; r < 4; ++r) {
      int b = wm * 64 + mi * 16 + lhi * 4 + r;
      dst[(long)b * 8192 + n] = f2bf(acc[mi][r]);
    }
}

// ---------------- E2: reduce xz bf16 partials + conv + SiLU ----------------
__global__ __launch_bounds__(256) void e2_conv(const unsigned short* __restrict__ xzp,
                                               const float* __restrict__ conv_state,
                                               const float* __restrict__ conv_w,
                                               const float* __restrict__ conv_b,
                                               float* __restrict__ out_ncs,
                                               float* __restrict__ xact_f,
                                               unsigned short* __restrict__ xact_b,
                                               unsigned short* __restrict__ szb) {
  int p = blockIdx.x * 256 + threadIdx.x;
  int b = p >> 12, n = p & 4095;
  long base = (long)b * 8192 + n;
  float xc = 0.f, z = 0.f;
#pragma unroll
  for (int s = 0; s < 4; ++s) {
    xc += bf2f(xzp[(long)s * (BATCH * 8192) + base]);
    z  += bf2f(xzp[(long)s * (BATCH * 8192) + base + DI]);
  }
  const float* cs = conv_state + (long)p * 3;
  float c0 = cs[0], c1 = cs[1], c2 = cs[2];
  f32x4 cw = *(const f32x4*)&conv_w[n * 4];
  float xs = c0 * cw[0] + c1 * cw[1] + c2 * cw[2] + xc * cw[3] + conv_b[n];
  float xa = xs * sigm(xs);
  float* ncs = out_ncs + (long)p * 3;
  ncs[0] = c1; ncs[1] = c2; ncs[2] = xc;
  xact_f[p] = xa;
  xact_b[p] = f2bf(xa);
  szb[p] = f2bf(z * sigm(z));
}

// ---------------- K3: x_proj GEMM (128x160x4096), gemmS, SK=32, f32 partials ----------------
__global__ __launch_bounds__(256, 4) void k3_xproj(const unsigned short* __restrict__ xact_b,
                                                   const float* __restrict__ XW,
                                                   float* __restrict__ projp) {
  __shared__ unsigned short lds[2 * 128 * LDT];
  f32x4 acc[4] = {};
  int bn = blockIdx.x, kc = blockIdx.y;
  gemmS(xact_b, DI, XW, DI, bn * 32, kc * 128, kc * 128 + 128, lds, acc);
  int tid = threadIdx.x, lane = tid & 63, wave = tid >> 6, wm = wave >> 1, wn = wave & 1;
  int llo = lane & 15, lhi = lane >> 4;
  int n = bn * 32 + wn * 16 + llo;
  float* dst = projp + (long)kc * (BATCH * 160);
#pragma unroll
  for (int mi = 0; mi < 4; ++mi)
#pragma unroll
    for (int r = 0; r < 4; ++r) {
      int b = wm * 64 + mi * 16 + lhi * 4 + r;
      dst[b * 160 + n] = acc[mi][r];
    }
}

// ---------------- K3r: reduce proj partials (32 -> 1) ----------------
__global__ __launch_bounds__(256) void k3r_reduce(const float* __restrict__ projp,
                                                  float* __restrict__ proj) {
  int t = blockIdx.x * 256 + threadIdx.x;
  f32x4 s = {};
#pragma unroll
  for (int k = 0; k < 32; ++k) {
    f32x4 v = *(const f32x4*)&projp[(long)k * (BATCH * 160) + t * 4];
    s[0] += v[0]; s[1] += v[1]; s[2] += v[2]; s[3] += v[3];
  }
  *(f32x4*)&proj[t * 4] = s;
}

// ---------------- K45: dt GEMM (32x32, K=128) + softplus + SSM + y*silu(z) ----------------
__global__ __launch_bounds__(256) void k45_dtssm(const float* __restrict__ proj,
                                                 const float* __restrict__ DW,
                                                 const float* __restrict__ dtb,
                                                 const float* __restrict__ A_log,
                                                 const float* __restrict__ Dp,
                                                 const float* __restrict__ ssm,
                                                 const float* __restrict__ xact_f,
                                                 const unsigned short* __restrict__ szb,
                                                 float* __restrict__ out_nss,
                                                 unsigned short* __restrict__ yz_b) {
  __shared__ unsigned short lds[2 * 64 * LDT];
  f32x4 acc[1] = {};
  int nb = blockIdx.x, mb = blockIdx.y;
  gemm32(proj, 160, DW, 128, mb * 32, nb * 32, 0, 128, lds, acc);
  int tid = threadIdx.x, lane = tid & 63, wave = tid >> 6, wm = wave >> 1, wn = wave & 1;
  int llo = lane & 15, lhi = lane >> 4;
  int n = nb * 32 + wn * 16 + llo;
  float dtbn = dtb[n], Dn = Dp[n];
  f32x4 Al0 = *(const f32x4*)&A_log[n * 16];
  f32x4 Al1 = *(const f32x4*)&A_log[n * 16 + 4];
  f32x4 Al2 = *(const f32x4*)&A_log[n * 16 + 8];
  f32x4 Al3 = *(const f32x4*)&A_log[n * 16 + 12];
  float aS[16];
#pragma unroll
  for (int j = 0; j < 4; ++j) {
    aS[j] = -__expf(Al0[j]); aS[4 + j] = -__expf(Al1[j]);
    aS[8 + j] = -__expf(Al2[j]); aS[12 + j] = -__expf(Al3[j]);
  }
#pragma unroll
  for (int r = 0; r < 4; ++r) {
    int b = mb * 32 + wm * 16 + lhi * 4 + r;
    long p = (long)b * DI + n;
    float v = acc[0][r] + dtbn;
    float dtv = (v > 20.f) ? v : log1pf(__expf(v));
    float xa = xact_f[p];
    const float* Bp = proj + b * 160 + 128;
    const float* Cp = proj + b * 160 + 144;
    const float* sp = ssm + p * 16;
    float* np = out_nss + p * 16;
    float y = 0.f;
#pragma unroll
    for (int q = 0; q < 4; ++q) {
      f32x4 sv = *(const f32x4*)&sp[q * 4];
      f32x4 Bv = *(const f32x4*)&Bp[q * 4];
      f32x4 Cv = *(const f32x4*)&Cp[q * 4];
      f32x4 nv;
#pragma unroll
      for (int j = 0; j < 4; ++j) {
        float dA = __expf(dtv * aS[q * 4 + j]);
        nv[j] = sv[j] * dA + dtv * Bv[j] * xa;
        y += nv[j] * Cv[j];
      }
      *(f32x4*)&np[q * 4] = nv;
    }
    yz_b[p] = f2bf((y + Dn * xa) * bf2f(szb[p]));
  }
}

// ---------------- K5: out_proj GEMM (128x2048x4096), gemmS, SK=8, f32 partials ----------------
__global__ __launch_bounds__(256, 4) void k5_outproj(const unsigned short* __restrict__ yz_b,
                                                     const float* __restrict__ OW,
                                                     float* __restrict__ op) {
  __shared__ unsigned short lds[2 * 128 * LDT];
  f32x4 acc[4] = {};
  int bn = blockIdx.x, sk = blockIdx.y;
  gemmS(yz_b, DI, OW, DI, bn * 32, sk * 512, sk * 512 + 512, lds, acc);
  int tid = threadIdx.x, lane = tid & 63, wave = tid >> 6, wm = wave >> 1, wn = wave & 1;
  int llo = lane & 15, lhi = lane >> 4;
  int n = bn * 32 + wn * 16 + llo;
  float* dst = op + (long)sk * (BATCH * DM);
#pragma unroll
  for (int mi = 0; mi < 4; ++mi)
#pragma unroll
    for (int r = 0; r < 4; ++r) {
      int b = wm * 64 + mi * 16 + lhi * 4 + r;
      dst[(long)b * DM + n] = acc[mi][r];
    }
}

// ---------------- K7: reduce out partials (8) + residual ----------------
__global__ __launch_bounds__(256) void k7_out(const float* __restrict__ op,
                                              const float* __restrict__ hs,
                                              float* __restrict__ outp) {
  int t = blockIdx.x * 256 + threadIdx.x;
  f32x4 s = *(const f32x4*)&hs[t * 4];
#pragma unroll
  for (int k = 0; k < 8; ++k) {
    f32x4 v = *(const f32x4*)&op[(long)k * (BATCH * DM) + t * 4];
    s[0] += v[0]; s[1] += v[1]; s[2] += v[2]; s[3] += v[3];
  }
  *(f32x4*)&outp[t * 4] = s;
}

extern "C" void kernel_launch(void* const* d_in, const int* in_sizes, int n_in, void* d_out,
                              int out_size, void* d_ws, size_t ws_size, hipStream_t stream) {
  const float* hs         = (const float*)d_in[0];
  const float* conv_state = (const float*)d_in[1];
  const float* ssm        = (const float*)d_in[2];
  const float* norm_w     = (const float*)d_in[3];
  const float* in_proj_w  = (const float*)d_in[4];
  const float* conv_w     = (const float*)d_in[5];
  const float* conv_b     = (const float*)d_in[6];
  const float* x_proj_w   = (const float*)d_in[7];
  const float* dt_proj_w  = (const float*)d_in[8];
  const float* dt_proj_b  = (const float*)d_in[9];
  const float* A_log      = (const float*)d_in[10];
  const float* Dp         = (const float*)d_in[11];
  const float* out_proj_w = (const float*)d_in[12];

  float* outp    = (float*)d_out;               // (128,1,2048)
  float* out_ncs = outp + 262144;               // (128,4096,3)
  float* out_nss = outp + 262144 + 1572864;     // (128,4096,16)

  char* ws = (char*)d_ws;
  unsigned short* normed = (unsigned short*)(ws);              // 0.5MB
  float*          xact_f = (float*)(ws + (1l << 20));          // 2MB
  unsigned short* xact_b = (unsigned short*)(ws + (3l << 20)); // 1MB
  unsigned short* szb    = (unsigned short*)(ws + (4l << 20)); // 1MB
  float*          proj   = (float*)(ws + (5l << 20));          // 80KB
  float*          projp  = (float*)(ws + (6l << 20));          // 2.5MB
  unsigned short* xzp    = (unsigned short*)(ws + (9l << 20)); // 4 x 2MB = 8MB (bf16)
  float*          op     = (float*)(ws + (18l << 20));         // 8 x 1MB = 8MB
  unsigned short* yz_b   = (unsigned short*)(ws + (27l << 20));// 1MB

  hipLaunchKernelGGL(k1_rmsnorm, dim3(128), dim3(256), 0, stream, hs, norm_w, normed);
  hipLaunchKernelGGL(k2_inproj, dim3(256, 4), dim3(256), 0, stream, normed, in_proj_w, xzp);
  hipLaunchKernelGGL(e2_conv, dim3(2048), dim3(256), 0, stream, xzp, conv_state, conv_w, conv_b,
                     out_ncs, xact_f, xact_b, szb);
  hipLaunchKernelGGL(k3_xproj, dim3(5, 32), dim3(256), 0, stream, xact_b, x_proj_w, projp);
  hipLaunchKernelGGL(k3r_reduce, dim3(20), dim3(256), 0, stream, projp, proj);
  hipLaunchKernelGGL(k45_dtssm, dim3(128, 4), dim3(256), 0, stream, proj, dt_proj_w, dt_proj_b,
                     A_log, Dp, ssm, xact_f, szb, out_nss, yz_b);
  hipLaunchKernelGGL(k5_outproj, dim3(64, 8), dim3(256), 0, stream, yz_b, out_proj_w, op);
  hipLaunchKernelGGL(k7_out, dim3(256), dim3(256), 0, stream, op, hs, outp);
}